// Round 3
// baseline (237.662 us; speedup 1.0000x reference)
//
#include <hip/hip_runtime.h>

// Smith-Waterman soft-DP, B=512, x: (512,151,151) f32, scalar output.
// One wave (64 threads) per batch. Slots j = 64*k + lane, k in {0,1,2}.
// All DP state in registers; neighbors via shuffles; no LDS, no barriers.
// State kept in base-2 (log2) domain: H = h * log2(e).

#define NEG2 (-1.4426950e30f)            // -1e30 * log2(e)
#define GO2  (-7.2134752044448170f)      // -5 * log2(e)
#define GE2  (-1.4426950408889634f)      // -1 * log2(e)
#define L2E  (1.4426950408889634f)
#define LN2  (0.6931471805599453f)

constexpr int NROW  = 151;
constexpr int NDIAG = 299;
constexpr int GUARD = 6;

#if __has_builtin(__builtin_amdgcn_exp2f)
#define EXP2(x) __builtin_amdgcn_exp2f(x)
#else
static __device__ __forceinline__ float EXP2_(float x){float r;asm("v_exp_f32 %0, %1":"=v"(r):"v"(x));return r;}
#define EXP2(x) EXP2_(x)
#endif

#if __has_builtin(__builtin_amdgcn_logf)
#define LOG2(x) __builtin_amdgcn_logf(x)
#else
static __device__ __forceinline__ float LOG2_(float x){float r;asm("v_log_f32 %0, %1":"=v"(r):"v"(x));return r;}
#define LOG2(x) LOG2_(x)
#endif

#if __has_builtin(__builtin_amdgcn_fmed3f)
#define MED3(a,b,c) __builtin_amdgcn_fmed3f(a,b,c)
#else
#define MED3(a,b,c) fmaxf(fminf(fmaxf(a,b),(c)), fminf(a,b))
#endif

static __device__ __forceinline__ float rl(float v, int l){
    return __int_as_float(__builtin_amdgcn_readlane(__float_as_int(v), l));
}

// valid-slot window on diagonal d: slots [jlo, jhi]
static __device__ __forceinline__ void window(int d, int& jlo, int& jhi){
    const int half = (149 + d) >> 1;
    jlo = half - (d < 149 ? d : 149);
    jhi = half - (d > 149 ? d - 149 : 0);
}

// per-register activity at diagonal dt (clamped), with guard band
static __device__ __forceinline__ void acts(int dt, bool& a0, bool& a1, bool& a2){
    dt = dt > 298 ? 298 : dt;
    int jlo, jhi; window(dt, jlo, jhi);
    a0 = (jlo - GUARD) <= 63;
    a1 = true;
    a2 = (jhi + GUARD) >= 128;
}

__global__ __launch_bounds__(64)
void sw_wave(const float* __restrict__ x, float* __restrict__ part,
             float* __restrict__ out_atomic, int use_atomic) {
    const int b = blockIdx.x;
    const float* xb = x + (size_t)b * (NROW * NROW);
    const int lane = threadIdx.x;

    float B[3][3], A[3][3], P0[3], P1[3], P2[3];
    #pragma unroll
    for (int k = 0; k < 3; ++k) {
        P0[k] = NEG2; P1[k] = NEG2; P2[k] = NEG2;
        #pragma unroll
        for (int c = 0; c < 3; ++c) { B[k][c] = NEG2; A[k][c] = NEG2; }
    }

    float M = NEG2, S = 0.0f;

    // prologue: preload sx(0) -> P0, sx(1) -> P1
    {
        #pragma unroll
        for (int dt = 0; dt < 2; ++dt) {
            bool a0, a1, a2; acts(dt, a0, a1, a2);
            const int half = (149 + dt) >> 1;
            float* P = dt ? P1 : P0;
            #pragma unroll
            for (int k = 0; k < 3; ++k) {
                const bool act = k == 0 ? a0 : (k == 1 ? a1 : a2);
                if (act) {
                    const int r = half - (64 * k + lane);
                    const int c = dt - r;
                    const bool fv = ((unsigned)r <= 150u) & ((unsigned)c <= 150u);
                    const int off = fv ? (r * NROW + c) : 0;
                    const float v = xb[off];
                    P[k] = fv ? v * L2E : NEG2;
                }
            }
        }
    }

    for (int d = 0; d < NDIAG; ++d) {
        const int so = d & 1;

        // ---- phase 1: gather h1 neighbors (pre-rotate B) ----
        float n0[3], n1[3], n2[3];
        if (so) {            // need h1[j-1], comps 0,1 (for "right")
            #pragma unroll
            for (int k = 0; k < 3; ++k) {
                n0[k] = __shfl_up(B[k][0], 1, 64);
                n1[k] = __shfl_up(B[k][1], 1, 64);
                n2[k] = NEG2;  // unused
            }
            const float e10 = rl(B[0][0], 63), e11 = rl(B[0][1], 63);
            const float e20 = rl(B[1][0], 63), e21 = rl(B[1][1], 63);
            if (lane == 0) {
                n0[0] = NEG2; n1[0] = NEG2;
                n0[1] = e10;  n1[1] = e11;
                n0[2] = e20;  n1[2] = e21;
            }
        } else {             // need h1[j+1], comps 0,1,2 (for "down")
            #pragma unroll
            for (int k = 0; k < 3; ++k) {
                n0[k] = __shfl_down(B[k][0], 1, 64);
                n1[k] = __shfl_down(B[k][1], 1, 64);
                n2[k] = __shfl_down(B[k][2], 1, 64);
            }
            const float f00 = rl(B[1][0], 0), f01 = rl(B[1][1], 0), f02 = rl(B[1][2], 0);
            const float f10 = rl(B[2][0], 0), f11 = rl(B[2][1], 0), f12 = rl(B[2][2], 0);
            if (lane == 63) {
                n0[0] = f00;  n1[0] = f01;  n2[0] = f02;
                n0[1] = f10;  n1[1] = f11;  n2[1] = f12;
                n0[2] = NEG2; n1[2] = NEG2; n2[2] = NEG2;
            }
        }

        // ---- phase 2: issue prefetch loads for sx(d+2); derive masks for d ----
        bool l0, l1, l2; acts(d + 2, l0, l1, l2);
        const int half2 = (151 + d) >> 1;     // row base for diag d+2
        float vraw[3], sxs[3];
        bool fvm[3], cvm[3];
        #pragma unroll
        for (int k = 0; k < 3; ++k) {
            const bool actl = k == 0 ? l0 : (k == 1 ? l1 : l2);
            fvm[k] = false; cvm[k] = false; vraw[k] = 0.0f; sxs[k] = NEG2;
            if (actl) {
                const int r2 = half2 - (64 * k + lane);
                const int c2 = (d + 2) - r2;
                const bool fv = ((unsigned)r2 <= 150u) & ((unsigned)c2 <= 150u);
                const bool cv = ((unsigned)(r2 - 1) <= 149u) & ((unsigned)(c2 - 1) <= 149u);
                const int off = fv ? (r2 * NROW + c2) : 0;
                vraw[k] = xb[off];                 // use deferred to phase 4
                fvm[k] = fv; cvm[k] = cv;
                sxs[k] = cv ? P0[k] : NEG2;        // sx(d), loaded 2 iters ago
            }
        }

        // ---- phase 3: per-register recurrence ----
        bool c0a, c1a, c2a; acts(d, c0a, c1a, c2a);
        float HO[3][3];
        #pragma unroll
        for (int k = 0; k < 3; ++k) {
            const bool act = k == 0 ? c0a : (k == 1 ? c1a : c2a);
            if (act) {
                // align = sx + lse2(A0,A1,A2,0)   [base-2]
                const float A0 = A[k][0], A1 = A[k][1], A2 = A[k][2];
                const float amx = fmaxf(fmaxf(A0, A1), A2);
                const float am  = fmaxf(amx, 0.0f);
                const float amn = fminf(fminf(A0, A1), A2);
                const float amd = MED3(A0, A1, A2);
                const float as  = 1.0f + EXP2(-fabsf(amx)) + EXP2(amn - am) + EXP2(amd - am);
                float h0v = sxs[k] + am + LOG2(as);

                float R0, R1, D0, D1, D2;
                if (so) { // right uses h1[j-1]; down uses own h1
                    R0 = n0[k] + GO2;    R1 = n1[k] + GE2;
                    D0 = B[k][0] + GO2;  D1 = B[k][1] + GO2;  D2 = B[k][2] + GE2;
                } else {  // right uses own h1; down uses h1[j+1]
                    R0 = B[k][0] + GO2;  R1 = B[k][1] + GE2;
                    D0 = n0[k] + GO2;    D1 = n1[k] + GO2;    D2 = n2[k] + GE2;
                }
                const float rm = fmaxf(R0, R1);
                float h1v = rm + LOG2(1.0f + EXP2(-fabsf(R0 - R1)));

                const float dmx = fmaxf(fmaxf(D0, D1), D2);
                const float dmn = fminf(fminf(D0, D1), D2);
                const float dmd = MED3(D0, D1, D2);
                float h2v = dmx + LOG2(1.0f + EXP2(dmn - dmx) + EXP2(dmd - dmx));

                if (k == 2 && lane >= 22) {   // slots >= 150: keep exact sentinel
                    h0v = NEG2; h1v = NEG2; h2v = NEG2;
                }
                HO[k][0] = h0v; HO[k][1] = h1v; HO[k][2] = h2v;
            }
        }

        // ---- phase 4: accumulate scores, rotate state, finalize prefetch ----
        #pragma unroll
        for (int k = 0; k < 3; ++k) {
            const bool act = k == 0 ? c0a : (k == 1 ? c1a : c2a);
            if (act) {
                const float x2v = cvm[k] ? vraw[k] * L2E : NEG2;  // x[b,1+r,1+c]
                const float s0 = HO[k][0] + x2v;
                const float s1 = HO[k][1] + x2v;
                const float s2 = HO[k][2] + x2v;
                const float smx = fmaxf(fmaxf(s0, s1), s2);
                const float Mn = fmaxf(M, smx);
                S = S * EXP2(M - Mn) + EXP2(s0 - Mn) + EXP2(s1 - Mn) + EXP2(s2 - Mn);
                M = Mn;
                A[k][0] = B[k][0]; A[k][1] = B[k][1]; A[k][2] = B[k][2];
                B[k][0] = HO[k][0]; B[k][1] = HO[k][1]; B[k][2] = HO[k][2];
            }
            const bool actl = k == 0 ? l0 : (k == 1 ? l1 : l2);
            P2[k] = (actl && fvm[k]) ? vraw[k] * L2E : NEG2;
            P0[k] = P1[k]; P1[k] = P2[k];
        }
    }

    // ---- wave-level online-lse reduction of (M,S) ----
    #pragma unroll
    for (int off = 32; off; off >>= 1) {
        const float Mo = __shfl_xor(M, off, 64);
        const float So = __shfl_xor(S, off, 64);
        const float Mn = fmaxf(M, Mo);
        S = S * EXP2(M - Mn) + So * EXP2(Mo - Mn);
        M = Mn;
    }
    if (lane == 0) {
        const float val = LN2 * (M + LOG2(S));
        if (use_atomic) atomicAdd(out_atomic, val);
        else            part[b] = val;
    }
}

__global__ __launch_bounds__(256)
void final_reduce(const float* __restrict__ part, float* __restrict__ out) {
    const int t = threadIdx.x;
    float v = part[t] + part[t + 256];
    #pragma unroll
    for (int off = 32; off; off >>= 1) v += __shfl_xor(v, off);
    __shared__ float ws[4];
    if ((t & 63) == 0) ws[t >> 6] = v;
    __syncthreads();
    if (t == 0) out[0] = ws[0] + ws[1] + ws[2] + ws[3];
}

extern "C" void kernel_launch(void* const* d_in, const int* in_sizes, int n_in,
                              void* d_out, int out_size, void* d_ws, size_t ws_size,
                              hipStream_t stream) {
    const float* x = (const float*)d_in[0];
    float* out = (float*)d_out;

    if (ws_size >= 512 * sizeof(float)) {
        float* part = (float*)d_ws;
        sw_wave<<<512, 64, 0, stream>>>(x, part, nullptr, 0);
        final_reduce<<<1, 256, 0, stream>>>(part, out);
    } else {
        hipMemsetAsync(out, 0, sizeof(float), stream);
        sw_wave<<<512, 64, 0, stream>>>(x, nullptr, out, 1);
    }
}

// Round 4
// 186.045 us; speedup vs baseline: 1.2774x; 1.2774x over previous
//
#include <hip/hip_runtime.h>

// Smith-Waterman soft-DP, B=512, x: (512,151,151) f32, scalar output.
// One wave per batch; slots j = 64k+lane, k=0..2; state in registers,
// neighbors via shuffles, 6-deep load pipeline, base-2 log domain.

#define NEG2 (-1.4426950e30f)            // -1e30 * log2(e)
#define GO2  (-7.2134752044448170f)      // -5 * log2(e)
#define GE2  (-1.4426950408889634f)      // -1 * log2(e)
#define L2E  (1.4426950408889634f)
#define LN2  (0.6931471805599453f)

#if __has_builtin(__builtin_amdgcn_exp2f)
#define EXP2(x) __builtin_amdgcn_exp2f(x)
#else
static __device__ __forceinline__ float EXP2_(float x){float r;asm("v_exp_f32 %0, %1":"=v"(r):"v"(x));return r;}
#define EXP2(x) EXP2_(x)
#endif

#if __has_builtin(__builtin_amdgcn_logf)
#define LOG2(x) __builtin_amdgcn_logf(x)
#else
static __device__ __forceinline__ float LOG2_(float x){float r;asm("v_log_f32 %0, %1":"=v"(r):"v"(x));return r;}
#define LOG2(x) LOG2_(x)
#endif

#if __has_builtin(__builtin_amdgcn_fmed3f)
#define MED3(a,b,c) __builtin_amdgcn_fmed3f(a,b,c)
#else
#define MED3(a,b,c) fmaxf(fminf(fmaxf(a,b),(c)), fminf(a,b))
#endif

static __device__ __forceinline__ float rl(float v, int l){
    return __int_as_float(__builtin_amdgcn_readlane(__float_as_int(v), l));
}

// One anti-diagonal step. SO = d&1 (compile-time).
// Invariant at entry: Q[i] = x-value (×L2E) for diag d+i (i=0..4, per slot),
// R = raw x-value for diag d+5. Loads issued here target diag d+6.
template<int SO>
static __device__ __forceinline__
void step(const int d, const float* __restrict__ xb, const int lane, const int j150,
          float (&B)[3][3], float (&A)[3][3], float (&Q)[5][3], float (&R)[3],
          const float M, float& S)
{
    // ---- wave-uniform scalars ----
    const int half  = (149 + d) >> 1;
    const int cvlo  = half - (d < 149 ? d : 149);          // core-window lo (slot)
    const int cvhi  = half - (d > 149 ? d - 149 : 0);      // core-window hi
    const bool cAct[3] = { cvlo <= 69, true, cvhi >= 122 };// guard=6 block gating
    const int t     = d + 6;                               // load target diag
    const int halfL = (149 + t) >> 1;
    const int jloF  = halfL - (t < 150 ? t : 150);         // full-matrix window
    const int jhiF  = halfL - (t > 150 ? t - 150 : 0);
    const bool dol  = t <= 300;
    const bool lAct[3] = { dol && (jloF <= 63),
                           dol && (jhiF >= 64) && (jloF <= 127),
                           dol && (jhiF >= 128) };
    const int selS  = 150 * halfL + t;                     // idx = selS - 150*j

    // ---- issue prefetch loads for diag d+6 (consumed >= 2 iters later) ----
    float ld[3] = {0.0f, 0.0f, 0.0f};
    #pragma unroll
    for (int k = 0; k < 3; ++k) {
        if (lAct[k]) {
            int idx = selS - j150 - 9600 * k;
            idx = idx < 0 ? 0 : idx;
            idx = idx > 22800 ? 22800 : idx;
            ld[k] = xb[idx];
        }
    }

    // ---- neighbor gather from h1 (=B) ----
    float n0[3], n1[3], n2[3];
    if (SO) {            // odd diag: "right" uses h1[j-1]
        #pragma unroll
        for (int k = 0; k < 3; ++k) if (cAct[k]) {
            n0[k] = __shfl_up(B[k][0], 1, 64);
            n1[k] = __shfl_up(B[k][1], 1, 64);
        }
        const float e10 = rl(B[0][0], 63), e11 = rl(B[0][1], 63);
        const float e20 = rl(B[1][0], 63), e21 = rl(B[1][1], 63);
        if (lane == 0) {
            n0[0] = NEG2; n1[0] = NEG2;
            n0[1] = e10;  n1[1] = e11;
            n0[2] = e20;  n1[2] = e21;
        }
    } else {             // even diag: "down" uses h1[j+1]
        #pragma unroll
        for (int k = 0; k < 3; ++k) if (cAct[k]) {
            n0[k] = __shfl_down(B[k][0], 1, 64);
            n1[k] = __shfl_down(B[k][1], 1, 64);
            n2[k] = __shfl_down(B[k][2], 1, 64);
        }
        const float f00 = rl(B[1][0], 0), f01 = rl(B[1][1], 0), f02 = rl(B[1][2], 0);
        const float f10 = rl(B[2][0], 0), f11 = rl(B[2][1], 0), f12 = rl(B[2][2], 0);
        if (lane == 63) {
            n0[0] = f00;  n1[0] = f01;  n2[0] = f02;
            n0[1] = f10;  n1[1] = f11;  n2[1] = f12;
            n0[2] = NEG2; n1[2] = NEG2; n2[2] = NEG2;
        }
    }

    // ---- per-block recurrence + score ----
    #pragma unroll
    for (int k = 0; k < 3; ++k) {
        if (!cAct[k]) continue;
        // per-lane core-cell mask for diag d (exact)
        const int lo = cvlo - 64 * k, hi = cvhi - 64 * k;
        const bool cv = (lane >= lo) && (lane <= hi);
        const float sx  = cv ? Q[0][k] : NEG2;    // x[r,c]   * L2E
        const float x2v = cv ? Q[2][k] : NEG2;    // x[r+1,c+1] * L2E

        // align = sx + lse2(A0,A1,A2,0)
        const float A0 = A[k][0], A1 = A[k][1], A2 = A[k][2];
        const float amx = fmaxf(fmaxf(A0, A1), A2);
        const float am  = fmaxf(amx, 0.0f);
        const float amn = fminf(fminf(A0, A1), A2);
        const float amd = MED3(A0, A1, A2);
        const float as  = 1.0f + EXP2(-fabsf(amx)) + EXP2(amn - am) + EXP2(amd - am);
        float h0v = sx + am + LOG2(as);

        float R0, R1, D0, D1, D2;
        if (SO) { // right from h1[j-1]; down from own h1
            R0 = n0[k] + GO2;    R1 = n1[k] + GE2;
            D0 = B[k][0] + GO2;  D1 = B[k][1] + GO2;  D2 = B[k][2] + GE2;
        } else {  // right from own h1; down from h1[j+1]
            R0 = B[k][0] + GO2;  R1 = B[k][1] + GE2;
            D0 = n0[k] + GO2;    D1 = n1[k] + GO2;    D2 = n2[k] + GE2;
        }
        const float rm = fmaxf(R0, R1);
        float h1v = rm + LOG2(1.0f + EXP2(-fabsf(R0 - R1)));

        const float dmx = fmaxf(fmaxf(D0, D1), D2);
        const float dmn = fminf(fminf(D0, D1), D2);
        const float dmd = MED3(D0, D1, D2);
        float h2v = dmx + LOG2(1.0f + EXP2(dmn - dmx) + EXP2(dmd - dmx));

        if (k == 2) {  // slots >= 150 don't exist: exact sentinel
            const bool pad = lane >= 22;
            h0v = pad ? NEG2 : h0v;
            h1v = pad ? NEG2 : h1v;
            h2v = pad ? NEG2 : h2v;
        }

        // score contribution: sc = x2 + lse3(h0,h1,h2); S += 2^(sc-M)
        const float smx = fmaxf(fmaxf(h0v, h1v), h2v);
        const float smn = fminf(fminf(h0v, h1v), h2v);
        const float smd = MED3(h0v, h1v, h2v);
        const float sc  = x2v + smx + LOG2(1.0f + EXP2(smn - smx) + EXP2(smd - smx));
        S += EXP2(sc - M);

        // rotate h-state
        A[k][0] = B[k][0]; A[k][1] = B[k][1]; A[k][2] = B[k][2];
        B[k][0] = h0v;     B[k][1] = h1v;     B[k][2] = h2v;
    }

    // ---- shift value FIFO; commit last iter's loads (vmcnt wait lands here) ----
    #pragma unroll
    for (int i = 0; i < 4; ++i) {
        Q[i][0] = Q[i + 1][0]; Q[i][1] = Q[i + 1][1]; Q[i][2] = Q[i + 1][2];
    }
    Q[4][0] = R[0] * L2E; Q[4][1] = R[1] * L2E; Q[4][2] = R[2] * L2E;
    R[0] = ld[0]; R[1] = ld[1]; R[2] = ld[2];
}

__global__ __launch_bounds__(64)
void sw_wave(const float* __restrict__ x, float* __restrict__ part,
             float* __restrict__ out_atomic, int use_atomic) {
    const int b = blockIdx.x;
    const float* xb = x + (size_t)b * (151 * 151);
    const int lane = threadIdx.x;
    const int j150 = 150 * lane;

    float B[3][3], A[3][3];
    #pragma unroll
    for (int k = 0; k < 3; ++k)
        #pragma unroll
        for (int c = 0; c < 3; ++c) { B[k][c] = NEG2; A[k][c] = NEG2; }

    float Q[5][3], R[3] = {0.0f, 0.0f, 0.0f};
    // prologue: diagonals 0..4 committed, 5 raw. Windows [halfL-t, halfL] are
    // all inside block k=1; k0/k2 slots masked at consumption.
    #pragma unroll
    for (int t = 0; t < 5; ++t) {
        Q[t][0] = 0.0f; Q[t][2] = 0.0f;
        const int halfL = (149 + t) >> 1;
        int idx = 150 * halfL + t - j150 - 9600;
        idx = idx < 0 ? 0 : idx;
        idx = idx > 22800 ? 22800 : idx;
        Q[t][1] = xb[idx] * L2E;
    }
    {
        int idx = 150 * 77 + 5 - j150 - 9600;
        idx = idx < 0 ? 0 : idx;
        idx = idx > 22800 ? 22800 : idx;
        R[1] = xb[idx];
    }

    float M = 0.0f, S = 0.0f;   // M wave-uniform by construction

    for (int d = 0; d < 298; d += 2) {
        step<0>(d,     xb, lane, j150, B, A, Q, R, M, S);
        step<1>(d + 1, xb, lane, j150, B, A, Q, R, M, S);
        if (__any(S > 1e18f)) { S *= 0x1p-64f; M += 64.0f; }
    }
    step<0>(298, xb, lane, j150, B, A, Q, R, M, S);

    // M is identical on all lanes -> batch lse = M + log2(sum_lanes S)
    #pragma unroll
    for (int off = 32; off; off >>= 1) S += __shfl_xor(S, off, 64);
    if (lane == 0) {
        const float val = LN2 * (M + LOG2(S));
        if (use_atomic) atomicAdd(out_atomic, val);
        else            part[b] = val;
    }
}

__global__ __launch_bounds__(256)
void final_reduce(const float* __restrict__ part, float* __restrict__ out) {
    const int t = threadIdx.x;
    float v = part[t] + part[t + 256];
    #pragma unroll
    for (int off = 32; off; off >>= 1) v += __shfl_xor(v, off);
    __shared__ float ws[4];
    if ((t & 63) == 0) ws[t >> 6] = v;
    __syncthreads();
    if (t == 0) out[0] = ws[0] + ws[1] + ws[2] + ws[3];
}

extern "C" void kernel_launch(void* const* d_in, const int* in_sizes, int n_in,
                              void* d_out, int out_size, void* d_ws, size_t ws_size,
                              hipStream_t stream) {
    const float* x = (const float*)d_in[0];
    float* out = (float*)d_out;

    if (ws_size >= 512 * sizeof(float)) {
        float* part = (float*)d_ws;
        sw_wave<<<512, 64, 0, stream>>>(x, part, nullptr, 0);
        final_reduce<<<1, 256, 0, stream>>>(part, out);
    } else {
        hipMemsetAsync(out, 0, sizeof(float), stream);
        sw_wave<<<512, 64, 0, stream>>>(x, nullptr, out, 1);
    }
}

// Round 5
// 122.430 us; speedup vs baseline: 1.9412x; 1.5196x over previous
//
#include <hip/hip_runtime.h>

// Smith-Waterman soft-DP, B=512, x: (512,151,151) f32, scalar output.
// One wave per batch; slots j = 64k+lane, k=0..2.
// LINEAR-DOMAIN DP: H = exp(h) * 2^-E (E wave-uniform block scale).
// Recurrence is pure FMA/add; neighbors via DPP; 7-diag load pipeline.

#define CGO 6.737946999085467e-03f   // e^-5
#define CGE 3.678794411714423e-01f   // e^-1
#define L2E 1.4426950408889634f
#define LN2 0.6931471805599453f
#define RTHR 0x1p60f
#define RSC  0x1p-64f

#if __has_builtin(__builtin_amdgcn_exp2f)
#define EXP2(x) __builtin_amdgcn_exp2f(x)
#else
static __device__ __forceinline__ float EXP2_(float x){float r;asm("v_exp_f32 %0, %1":"=v"(r):"v"(x));return r;}
#define EXP2(x) EXP2_(x)
#endif

#if __has_builtin(__builtin_amdgcn_logf)
#define LOG2(x) __builtin_amdgcn_logf(x)
#else
static __device__ __forceinline__ float LOG2_(float x){float r;asm("v_log_f32 %0, %1":"=v"(r):"v"(x));return r;}
#define LOG2(x) LOG2_(x)
#endif

static __device__ __forceinline__ float rl(float v, int l){
    return __int_as_float(__builtin_amdgcn_readlane(__float_as_int(v), l));
}

// DPP lane shifts: wave_shr:1 (0x138) = lane i <- i-1 (shfl_up);
//                  wave_shl:1 (0x130) = lane i <- i+1 (shfl_down).
#define DPP_UP 0x138
#define DPP_DN 0x130

template<int CTRL>
static __device__ __forceinline__ float dppz(float v){   // invalid lanes -> 0
    return __int_as_float(__builtin_amdgcn_update_dpp(
        0, __float_as_int(v), CTRL, 0xF, 0xF, true));
}
template<int CTRL>
static __device__ __forceinline__ float dppc(float old, float v){ // invalid lanes -> old
    return __int_as_float(__builtin_amdgcn_update_dpp(
        __float_as_int(old), __float_as_int(v), CTRL, 0xF, 0xF, false));
}

// One anti-diagonal step (SO = d&1, compile-time).
// Entry invariant: Q[i][k] = exp(x) for diag d+i (i=0..2);
//                  R[i][k] = raw x for diag d+3+i (i=0..3).
// Loads issued here target diag d+7.
template<int SO>
static __device__ __forceinline__
void step(const int d, const float* __restrict__ xb, const int lane, const int j150,
          float (&B)[3][3], float (&A)[3][3], float (&Q)[3][3], float (&R)[4][3],
          const float oneE, float& S)
{
    // ---- wave-uniform scalars ----
    const int half  = (149 + d) >> 1;
    const int cvlo  = half - (d < 149 ? d : 149);          // core window lo
    const int cvhi  = half - (d > 149 ? d - 149 : 0);      // core window hi
    const bool cAct[3] = { cvlo <= 69, true, cvhi >= 122 };
    const int t     = d + 7;                               // load target diag
    const int halfL = (149 + t) >> 1;
    const int jloF  = halfL - (t < 150 ? t : 150);         // full-matrix window
    const int jhiF  = halfL - (t > 150 ? t - 150 : 0);
    const bool dol  = t <= 300;
    const bool lAct[3] = { dol && (jloF <= 63),
                           dol && (jhiF >= 64) && (jloF <= 127),
                           dol && (jhiF >= 128) };
    const int selS  = 150 * halfL + t;                     // idx = selS - 150*j

    // ---- issue prefetch loads for diag d+7 ----
    float ld[3] = {0.0f, 0.0f, 0.0f};
    #pragma unroll
    for (int k = 0; k < 3; ++k) {
        if (lAct[k]) {
            int idx = selS - j150 - 9600 * k;
            idx = idx < 0 ? 0 : idx;
            idx = idx > 22800 ? 22800 : idx;
            ld[k] = xb[idx];
        }
    }

    // ---- neighbor gather from h1 (=B) via DPP ----
    float n0[3], n1[3], n2[3];
    if (SO) {   // odd: "right" uses h1[j-1], comps 0,1
        n0[0] = dppz<DPP_UP>(B[0][0]);
        n1[0] = dppz<DPP_UP>(B[0][1]);
        n0[1] = dppc<DPP_UP>(rl(B[0][0], 63), B[1][0]);
        n1[1] = dppc<DPP_UP>(rl(B[0][1], 63), B[1][1]);
        n0[2] = dppc<DPP_UP>(rl(B[1][0], 63), B[2][0]);
        n1[2] = dppc<DPP_UP>(rl(B[1][1], 63), B[2][1]);
        n2[0] = n2[1] = n2[2] = 0.0f;
    } else {    // even: "down" uses h1[j+1], comps 0,1,2
        n0[2] = dppz<DPP_DN>(B[2][0]);
        n1[2] = dppz<DPP_DN>(B[2][1]);
        n2[2] = dppz<DPP_DN>(B[2][2]);
        n0[1] = dppc<DPP_DN>(rl(B[2][0], 0), B[1][0]);
        n1[1] = dppc<DPP_DN>(rl(B[2][1], 0), B[1][1]);
        n2[1] = dppc<DPP_DN>(rl(B[2][2], 0), B[1][2]);
        n0[0] = dppc<DPP_DN>(rl(B[1][0], 0), B[0][0]);
        n1[0] = dppc<DPP_DN>(rl(B[1][1], 0), B[0][1]);
        n2[0] = dppc<DPP_DN>(rl(B[1][2], 0), B[0][2]);
    }

    // ---- per-block recurrence + score (pure FMA) ----
    #pragma unroll
    for (int k = 0; k < 3; ++k) {
        if (!cAct[k]) continue;
        const int lo = cvlo - 64 * k, hi = cvhi - 64 * k;
        const bool cv = (lane >= lo) && (lane <= hi);
        const float sxl = cv ? Q[0][k] : 0.0f;    // exp(x[r,c])
        const float x2l = cv ? Q[2][k] : 0.0f;    // exp(x[r+1,c+1])

        float h0 = sxl * (((A[k][0] + A[k][1]) + A[k][2]) + oneE);
        float h1, h2;
        if (SO) {
            h1 = fmaf(CGO, n0[k], CGE * n1[k]);
            h2 = fmaf(CGO, B[k][0] + B[k][1], CGE * B[k][2]);
        } else {
            h1 = fmaf(CGO, B[k][0], CGE * B[k][1]);
            h2 = fmaf(CGO, n0[k] + n1[k], CGE * n2[k]);
        }
        if (k == 2) {   // slots >= 150 don't exist
            const bool pad = lane >= 22;
            h0 = pad ? 0.0f : h0;
            h1 = pad ? 0.0f : h1;
            h2 = pad ? 0.0f : h2;
        }
        S = fmaf(x2l, (h0 + h1) + h2, S);
        A[k][0] = B[k][0]; A[k][1] = B[k][1]; A[k][2] = B[k][2];
        B[k][0] = h0;      B[k][1] = h1;      B[k][2] = h2;
    }

    // ---- FIFO: commit exp of oldest raw; shift; insert new loads ----
    #pragma unroll
    for (int k = 0; k < 3; ++k) {
        Q[0][k] = Q[1][k]; Q[1][k] = Q[2][k];
        Q[2][k] = EXP2(R[0][k] * L2E);
        R[0][k] = R[1][k]; R[1][k] = R[2][k]; R[2][k] = R[3][k];
        R[3][k] = ld[k];
    }
}

__global__ __launch_bounds__(64)
void sw_wave(const float* __restrict__ x, float* __restrict__ part,
             float* __restrict__ out_atomic, int use_atomic) {
    const int b = blockIdx.x;
    const float* xb = x + (size_t)b * (151 * 151);
    const int lane = threadIdx.x;
    const int j150 = 150 * lane;

    float B[3][3], A[3][3], Q[3][3], R[4][3];
    #pragma unroll
    for (int k = 0; k < 3; ++k)
        #pragma unroll
        for (int c = 0; c < 3; ++c) { B[k][c] = 0.0f; A[k][c] = 0.0f; }
    #pragma unroll
    for (int i = 0; i < 3; ++i) { Q[i][0] = 0.0f; Q[i][2] = 0.0f; }
    #pragma unroll
    for (int i = 0; i < 4; ++i) { R[i][0] = 0.0f; R[i][2] = 0.0f; }

    // prologue: diags 0..2 committed (exp), 3..6 raw. Windows all in k=1.
    #pragma unroll
    for (int t = 0; t < 3; ++t) {
        const int halfL = (149 + t) >> 1;
        int idx = 150 * halfL + t - j150 - 9600;
        idx = idx < 0 ? 0 : idx; idx = idx > 22800 ? 22800 : idx;
        Q[t][1] = EXP2(xb[idx] * L2E);
    }
    #pragma unroll
    for (int t = 3; t < 7; ++t) {
        const int halfL = (149 + t) >> 1;
        int idx = 150 * halfL + t - j150 - 9600;
        idx = idx < 0 ? 0 : idx; idx = idx > 22800 ? 22800 : idx;
        R[t - 3][1] = xb[idx];
    }

    float oneE = 1.0f;   // 2^-E
    float E = 0.0f;      // wave-uniform block-scale exponent
    float S = 0.0f;      // per-lane score sum, scaled by 2^-E

    for (int d = 0; d < 298; d += 2) {
        step<0>(d,     xb, lane, j150, B, A, Q, R, oneE, S);
        step<1>(d + 1, xb, lane, j150, B, A, Q, R, oneE, S);
        // renorm check (wave-uniform branch, triggers ~once per batch)
        float m = B[0][0];
        m = fmaxf(m, B[0][1]); m = fmaxf(m, B[0][2]);
        m = fmaxf(m, B[1][0]); m = fmaxf(m, B[1][1]); m = fmaxf(m, B[1][2]);
        m = fmaxf(m, B[2][0]); m = fmaxf(m, B[2][1]); m = fmaxf(m, B[2][2]);
        if (__any(m > RTHR)) {
            #pragma unroll
            for (int k = 0; k < 3; ++k)
                #pragma unroll
                for (int c = 0; c < 3; ++c) { A[k][c] *= RSC; B[k][c] *= RSC; }
            S *= RSC; oneE *= RSC; E += 64.0f;
        }
    }
    step<0>(298, xb, lane, j150, B, A, Q, R, oneE, S);

    // wave sum of S (E uniform across lanes)
    #pragma unroll
    for (int off = 32; off; off >>= 1) S += __shfl_xor(S, off, 64);
    if (lane == 0) {
        const float val = LN2 * (E + LOG2(S));
        if (use_atomic) atomicAdd(out_atomic, val);
        else            part[b] = val;
    }
}

__global__ __launch_bounds__(256)
void final_reduce(const float* __restrict__ part, float* __restrict__ out) {
    const int t = threadIdx.x;
    float v = part[t] + part[t + 256];
    #pragma unroll
    for (int off = 32; off; off >>= 1) v += __shfl_xor(v, off);
    __shared__ float ws[4];
    if ((t & 63) == 0) ws[t >> 6] = v;
    __syncthreads();
    if (t == 0) out[0] = ws[0] + ws[1] + ws[2] + ws[3];
}

extern "C" void kernel_launch(void* const* d_in, const int* in_sizes, int n_in,
                              void* d_out, int out_size, void* d_ws, size_t ws_size,
                              hipStream_t stream) {
    const float* x = (const float*)d_in[0];
    float* out = (float*)d_out;

    if (ws_size >= 512 * sizeof(float)) {
        float* part = (float*)d_ws;
        sw_wave<<<512, 64, 0, stream>>>(x, part, nullptr, 0);
        final_reduce<<<1, 256, 0, stream>>>(part, out);
    } else {
        hipMemsetAsync(out, 0, sizeof(float), stream);
        sw_wave<<<512, 64, 0, stream>>>(x, nullptr, out, 1);
    }
}